// Round 16
// baseline (166.485 us; speedup 1.0000x reference)
//
#include <hip/hip_runtime.h>

// SKA3D: x [B=2, C=64, D=64, H=64, W=64] fp32; w [B=2, G=8, 27, D, H, W] fp32
// out[b,c,d,h,w] = sum_k x[b,c,(d+di)%64,(h+hi)%64,(w+wi)%64] * w[b,c/8,k,d,h,w]
//
// R16 = R15/R9 champion body, byte-identical, with an XCD-partitioned grid
// decode: XCD k (dispatch round-robins bid%8 across XCDs) owns exactly two
// (b,g) slabs, so the ~96 co-resident blocks per XCD share one 8 MB x slab
// in their 4 MB L2 — staging-halo refetches (dc+-1, ht+-1 neighbors, adjacent
// in the within-XCD order s) hit L2 instead of resolving in L3.
//   bid -> xcd = bid&7, s = bid>>3; bg = xcd*2 + (s>>7); ht=(s>>3)&15; dc=s&7
// (bijective over 2048 = 8 xcd x 2 bg x 16 ht x 8 dc.)
//
// Champion structure (R9, reproduced 156.3/156.25 us):
//  - 4-wave block, 2 ch/wave; 4-slot d-sliding LDS ring [slot][c][r][w] 48 KB
//  - staging via global_load_lds width=16, linear LDS dest
//  - b128-only LDS reads; W-halos via DPP row_ror (VALU pipe, conflict-free)
//  - wk[27] single-buffered, loaded MONOLITHICALLY at loop end (chunked /
//    hoisted / touched variants all spilled or regressed: R6/R7/R10/R11/R14)
//  - raw s_barrier + counted vmcnt; nontemporal stores; waves_per_eu(2,3)
//
// Per-wave per-iter VMEM order: stage(3), stores(2), wk(27).
// [A] vmcnt(29) drains my stage(d+1) (newer: 2 stores + 27 wk = 29).
// [B] s_barrier -> slot d+1 globally ready AND nobody still reads slot (d+2)&3.

#define ND 64
#define NH 64
#define NW 64
#define HW 4096
#define DHW 262144

typedef const __attribute__((address_space(1))) unsigned int* gp_as1;
typedef __attribute__((address_space(3))) unsigned int* lp_as3;
typedef float f32x4 __attribute__((ext_vector_type(4)));

__device__ __forceinline__ float dpp_prev(float v) {   // lane j <- lane (j-1)&15
    int i = __builtin_bit_cast(int, v);
    i = __builtin_amdgcn_update_dpp(i, i, 0x121, 0xF, 0xF, true);  // row_ror:1
    return __builtin_bit_cast(float, i);
}
__device__ __forceinline__ float dpp_next(float v) {   // lane j <- lane (j+1)&15
    int i = __builtin_bit_cast(int, v);
    i = __builtin_amdgcn_update_dpp(i, i, 0x12F, 0xF, 0xF, true);  // row_ror:15
    return __builtin_bit_cast(float, i);
}

__global__ __launch_bounds__(256)
__attribute__((amdgpu_waves_per_eu(2, 3)))
void ska3d_kernel(const float* __restrict__ x,
                  const float* __restrict__ w,
                  float* __restrict__ out) {
    __shared__ float lds[4][8][6][NW];     // [slot][c][r][w] 48 KB

    const int tid  = threadIdx.x;          // 0..255
    const int lane = tid & 63;
    const int wv   = tid >> 6;             // wave id 0..3
    const int w0   = (lane & 15) * 4;      // w strip start
    const int hl   = lane >> 4;            // 0..3
    const int c0   = wv * 2;               // this wave's channels

    // XCD-partitioned decode: XCD (bid&7) owns (b,g) pair 2*xcd .. 2*xcd+1
    const int bid = blockIdx.x;
    const int xcd = bid & 7;
    const int s   = bid >> 3;              // 0..255 within-XCD sequence
    const int bg  = xcd * 2 + (s >> 7);    // 0..15
    const int ht  = (s >> 3) & 15;         // h-tile (4 rows)
    const int dc  = s & 7;                 // d-chunk (8 planes)
    const int g   = bg & 7;
    const int b   = bg >> 3;

    const int d0 = dc * 8;
    const int h0 = ht * 4;
    const int h  = h0 + hl;

    const float* xb = x + (size_t)(b * 64 + g * 8) * DHW;
    const float* wb = w + (size_t)(b * 8 + g) * 27 * DHW + h * NW + w0;
    float* ob = out + (size_t)(b * 64 + g * 8 + c0) * DHW + h * NW + w0;

    // stage plane p: 768 16B-units, 256 threads -> 3 ops/thread
#define STAGE(p) do {                                                          \
        const int slot_ = (p) & 3;                                             \
        const int dd_   = (p) & 63;                                            \
        _Pragma("unroll")                                                      \
        for (int i_ = 0; i_ < 3; ++i_) {                                       \
            const int fid = i_ * 256 + tid;    /* 0..767 */                    \
            const int c_  = fid / 96;                                          \
            const int rm_ = fid - c_ * 96;                                     \
            const int r_  = rm_ >> 4;          /* 0..5 */                      \
            const int ws_ = rm_ & 15;          /* 0..15 */                     \
            const int hh_ = (h0 - 1 + r_) & 63;                                \
            const float* gsrc = xb + (size_t)c_ * DHW + dd_ * HW + hh_ * NW + ws_ * 4; \
            __builtin_amdgcn_global_load_lds((gp_as1)gsrc,                     \
                (lp_as3)&lds[slot_][c_][r_][ws_ * 4], 16, 0, 0);               \
        }                                                                      \
    } while (0)

#define LOADW(dp) do {                                                         \
        const float* wp_ = wb + (size_t)(dp) * HW;                             \
        _Pragma("unroll")                                                      \
        for (int k_ = 0; k_ < 27; ++k_)                                        \
            wk[k_] = *(const float4*)(wp_ + (size_t)k_ * DHW);                 \
    } while (0)

    float4 wk[27];

    // prologue: planes d0-1, d0, d0+1 staged; wk(d0) loaded; full drain
    STAGE(d0 - 1);
    STAGE(d0);
    STAGE(d0 + 1);
    LOADW(d0);
    asm volatile("s_waitcnt vmcnt(0)" ::: "memory");

#pragma unroll 1
    for (int i = 0; i < 8; ++i) {
        const int d = d0 + i;

        // [A] drain my stage(d+1); newer ops = 2 stores + 27 wk = 29
        asm volatile("s_waitcnt vmcnt(29)" ::: "memory");
        // [B] all waves' stage(d+1) done; all waves done reading slot (d+2)&3
        asm volatile("s_barrier" ::: "memory");

        // [C] prefetch plane d+2 into slot (d+2)&3 (disjoint from d-1,d,d+1)
        if (i < 7) STAGE(d + 2);

        // [D] compute plane d: one b128 LDS read per (di,hi,cc); halos via DPP
        float acc[2][4];
#pragma unroll
        for (int cc = 0; cc < 2; ++cc)
            acc[cc][0] = acc[cc][1] = acc[cc][2] = acc[cc][3] = 0.f;

#pragma unroll
        for (int di = -1; di <= 1; ++di) {
            const int slot = (d + di) & 3;
#pragma unroll
            for (int hi = -1; hi <= 1; ++hi) {
                const int r  = hl + hi + 1;            // 0..5
                const int kb = (di + 1) * 9 + (hi + 1) * 3;
#pragma unroll
                for (int cc = 0; cc < 2; ++cc) {
                    const float* row = &lds[slot][c0 + cc][r][0];
                    const float4 xv = *(const float4*)(row + w0);
                    const float  xm = dpp_prev(xv.w);   // x[w0-1] (circular)
                    const float  xp = dpp_next(xv.x);   // x[w0+4] (circular)
                    const float4 wa = wk[kb], wm = wk[kb + 1], wc = wk[kb + 2];
                    acc[cc][0] += wa.x * xm;    acc[cc][1] += wa.y * xv.x;
                    acc[cc][2] += wa.z * xv.y;  acc[cc][3] += wa.w * xv.z;
                    acc[cc][0] += wm.x * xv.x;  acc[cc][1] += wm.y * xv.y;
                    acc[cc][2] += wm.z * xv.z;  acc[cc][3] += wm.w * xv.w;
                    acc[cc][0] += wc.x * xv.y;  acc[cc][1] += wc.y * xv.z;
                    acc[cc][2] += wc.z * xv.w;  acc[cc][3] += wc.w * xp;
                }
            }
        }

        // [E] nontemporal stores (out is never re-read)
#pragma unroll
        for (int cc = 0; cc < 2; ++cc) {
            f32x4 v;
            v.x = acc[cc][0]; v.y = acc[cc][1]; v.z = acc[cc][2]; v.w = acc[cc][3];
            __builtin_nontemporal_store(v,
                (f32x4*)(ob + (size_t)cc * DHW + (size_t)d * HW));
        }

        // [F] wk(d+1) for next iteration (whole, at loop end — proven shape)
        if (i < 7) LOADW(d + 1);
    }
}

extern "C" void kernel_launch(void* const* d_in, const int* in_sizes, int n_in,
                              void* d_out, int out_size, void* d_ws, size_t ws_size,
                              hipStream_t stream) {
    const float* x = (const float*)d_in[0];
    const float* w = (const float*)d_in[1];
    float* out = (float*)d_out;
    // grid: 8 XCDs x (2 bg x 16 ht x 8 dc) = 2048 blocks of 256
    dim3 grid(2048);
    dim3 block(256);
    hipLaunchKernelGGL(ska3d_kernel, grid, block, 0, stream, x, w, out);
}

// Round 17
// 156.961 us; speedup vs baseline: 1.0607x; 1.0607x over previous
//
#include <hip/hip_runtime.h>

// SKA3D: x [B=2, C=64, D=64, H=64, W=64] fp32; w [B=2, G=8, 27, D, H, W] fp32
// out[b,c,d,h,w] = sum_k x[b,c,(d+di)%64,(h+hi)%64,(w+wi)%64] * w[b,c/8,k,d,h,w]
//
// FINAL = R9/R15 champion (156.3 / 156.25 us, reproduced twice):
//  - 4-wave block, 2 ch/wave; 4-slot d-sliding LDS ring [slot][c][r][w] 48 KB
//  - staging via global_load_lds width=16, linear LDS dest
//  - b128-only LDS reads; W-halos via DPP row_ror on the VALU pipe
//  - wk[27] single-buffered, loaded MONOLITHICALLY at loop end
//  - raw s_barrier + counted vmcnt; nontemporal stores; waves_per_eu(2,3)
// Measured-refuted alternatives: reg-dbuf wk (spill x4), touch-prefetch (-8%),
// h-slide (-10%), h-tile-8 (-29%), d-chunk-16 (neutral), XCD partition (-7%).
// Equilibrium: ~3 waves/SIMD (VGPR) x 3 blocks/CU (LDS 144/160 KB); ~4.5 TB/s
// effective on ~660 MB traffic — DRAM-pattern-limited (27 x 1KB-granule
// streams); practical roofline for this structure.
//
// Per-wave per-iter VMEM order: stage(3), stores(2), wk(27).
// [A] vmcnt(29) drains my stage(d+1) (newer: 2 stores + 27 wk = 29).
// [B] s_barrier -> slot d+1 globally ready AND nobody still reads slot (d+2)&3.

#define ND 64
#define NH 64
#define NW 64
#define HW 4096
#define DHW 262144

typedef const __attribute__((address_space(1))) unsigned int* gp_as1;
typedef __attribute__((address_space(3))) unsigned int* lp_as3;
typedef float f32x4 __attribute__((ext_vector_type(4)));

__device__ __forceinline__ float dpp_prev(float v) {   // lane j <- lane (j-1)&15
    int i = __builtin_bit_cast(int, v);
    i = __builtin_amdgcn_update_dpp(i, i, 0x121, 0xF, 0xF, true);  // row_ror:1
    return __builtin_bit_cast(float, i);
}
__device__ __forceinline__ float dpp_next(float v) {   // lane j <- lane (j+1)&15
    int i = __builtin_bit_cast(int, v);
    i = __builtin_amdgcn_update_dpp(i, i, 0x12F, 0xF, 0xF, true);  // row_ror:15
    return __builtin_bit_cast(float, i);
}

__global__ __launch_bounds__(256)
__attribute__((amdgpu_waves_per_eu(2, 3)))
void ska3d_kernel(const float* __restrict__ x,
                  const float* __restrict__ w,
                  float* __restrict__ out) {
    __shared__ float lds[4][8][6][NW];     // [slot][c][r][w] 48 KB

    const int tid  = threadIdx.x;          // 0..255
    const int lane = tid & 63;
    const int wv   = tid >> 6;             // wave id 0..3
    const int w0   = (lane & 15) * 4;      // w strip start
    const int hl   = lane >> 4;            // 0..3
    const int c0   = wv * 2;               // this wave's channels

    const int bid = blockIdx.x;
    const int dc  = bid & 7;               // d-chunk (8 planes)
    const int ht  = (bid >> 3) & 15;       // h-tile (4 rows)
    const int g   = (bid >> 7) & 7;
    const int b   = bid >> 10;

    const int d0 = dc * 8;
    const int h0 = ht * 4;
    const int h  = h0 + hl;

    const float* xb = x + (size_t)(b * 64 + g * 8) * DHW;
    const float* wb = w + (size_t)(b * 8 + g) * 27 * DHW + h * NW + w0;
    float* ob = out + (size_t)(b * 64 + g * 8 + c0) * DHW + h * NW + w0;

    // stage plane p: 768 16B-units, 256 threads -> 3 ops/thread
#define STAGE(p) do {                                                          \
        const int slot_ = (p) & 3;                                             \
        const int dd_   = (p) & 63;                                            \
        _Pragma("unroll")                                                      \
        for (int i_ = 0; i_ < 3; ++i_) {                                       \
            const int fid = i_ * 256 + tid;    /* 0..767 */                    \
            const int c_  = fid / 96;                                          \
            const int rm_ = fid - c_ * 96;                                     \
            const int r_  = rm_ >> 4;          /* 0..5 */                      \
            const int ws_ = rm_ & 15;          /* 0..15 */                     \
            const int hh_ = (h0 - 1 + r_) & 63;                                \
            const float* gsrc = xb + (size_t)c_ * DHW + dd_ * HW + hh_ * NW + ws_ * 4; \
            __builtin_amdgcn_global_load_lds((gp_as1)gsrc,                     \
                (lp_as3)&lds[slot_][c_][r_][ws_ * 4], 16, 0, 0);               \
        }                                                                      \
    } while (0)

#define LOADW(dp) do {                                                         \
        const float* wp_ = wb + (size_t)(dp) * HW;                             \
        _Pragma("unroll")                                                      \
        for (int k_ = 0; k_ < 27; ++k_)                                        \
            wk[k_] = *(const float4*)(wp_ + (size_t)k_ * DHW);                 \
    } while (0)

    float4 wk[27];

    // prologue: planes d0-1, d0, d0+1 staged; wk(d0) loaded; full drain
    STAGE(d0 - 1);
    STAGE(d0);
    STAGE(d0 + 1);
    LOADW(d0);
    asm volatile("s_waitcnt vmcnt(0)" ::: "memory");

#pragma unroll 1
    for (int i = 0; i < 8; ++i) {
        const int d = d0 + i;

        // [A] drain my stage(d+1); newer ops = 2 stores + 27 wk = 29
        asm volatile("s_waitcnt vmcnt(29)" ::: "memory");
        // [B] all waves' stage(d+1) done; all waves done reading slot (d+2)&3
        asm volatile("s_barrier" ::: "memory");

        // [C] prefetch plane d+2 into slot (d+2)&3 (disjoint from d-1,d,d+1)
        if (i < 7) STAGE(d + 2);

        // [D] compute plane d: one b128 LDS read per (di,hi,cc); halos via DPP
        float acc[2][4];
#pragma unroll
        for (int cc = 0; cc < 2; ++cc)
            acc[cc][0] = acc[cc][1] = acc[cc][2] = acc[cc][3] = 0.f;

#pragma unroll
        for (int di = -1; di <= 1; ++di) {
            const int slot = (d + di) & 3;
#pragma unroll
            for (int hi = -1; hi <= 1; ++hi) {
                const int r  = hl + hi + 1;            // 0..5
                const int kb = (di + 1) * 9 + (hi + 1) * 3;
#pragma unroll
                for (int cc = 0; cc < 2; ++cc) {
                    const float* row = &lds[slot][c0 + cc][r][0];
                    const float4 xv = *(const float4*)(row + w0);
                    const float  xm = dpp_prev(xv.w);   // x[w0-1] (circular)
                    const float  xp = dpp_next(xv.x);   // x[w0+4] (circular)
                    const float4 wa = wk[kb], wm = wk[kb + 1], wc = wk[kb + 2];
                    acc[cc][0] += wa.x * xm;    acc[cc][1] += wa.y * xv.x;
                    acc[cc][2] += wa.z * xv.y;  acc[cc][3] += wa.w * xv.z;
                    acc[cc][0] += wm.x * xv.x;  acc[cc][1] += wm.y * xv.y;
                    acc[cc][2] += wm.z * xv.z;  acc[cc][3] += wm.w * xv.w;
                    acc[cc][0] += wc.x * xv.y;  acc[cc][1] += wc.y * xv.z;
                    acc[cc][2] += wc.z * xv.w;  acc[cc][3] += wc.w * xp;
                }
            }
        }

        // [E] nontemporal stores (out is never re-read)
#pragma unroll
        for (int cc = 0; cc < 2; ++cc) {
            f32x4 v;
            v.x = acc[cc][0]; v.y = acc[cc][1]; v.z = acc[cc][2]; v.w = acc[cc][3];
            __builtin_nontemporal_store(v,
                (f32x4*)(ob + (size_t)cc * DHW + (size_t)d * HW));
        }

        // [F] wk(d+1) for next iteration (whole, at loop end — proven shape)
        if (i < 7) LOADW(d + 1);
    }
}

extern "C" void kernel_launch(void* const* d_in, const int* in_sizes, int n_in,
                              void* d_out, int out_size, void* d_ws, size_t ws_size,
                              hipStream_t stream) {
    const float* x = (const float*)d_in[0];
    const float* w = (const float*)d_in[1];
    float* out = (float*)d_out;
    // grid: b(2) x g(8) x h-tiles(16) x d-chunks(8) = 2048 blocks of 256
    dim3 grid(2048);
    dim3 block(256);
    hipLaunchKernelGGL(ska3d_kernel, grid, block, 0, stream, x, w, out);
}